// Round 4
// baseline (4255.725 us; speedup 1.0000x reference)
//
#include <hip/hip_runtime.h>
#include <hip/hip_bf16.h>

// N=512, T=64, D=512, H=512, 4H=2048, K = D+2H = 1536
// Round 4: rounds 2/3 gave BIT-IDENTICAL absmax (1.5625) across a 200x GEMM
// precision change => failure is not precision; inputs are likely stored bf16
// (stub absmax 0.9296875 is exactly bf16-grid; test label says bf16).
// Fix: runtime dtype detector (even-index-ushort bf16 decode: junk-exponent
// test) + dual-path loads + dual-path output store. GEMM: x64-scaled
// split-fp16 3-term (exact for bf16 inputs; ~2.5e-7 rel for fp32 inputs).
#define NB   512
#define TS   64
#define KTOT 1536
#define OPSCALE 64.0f
#define INV_SCALE2 (1.0f / 4096.0f)

typedef _Float16 f16x8 __attribute__((ext_vector_type(8)));
typedef float    f32x4 __attribute__((ext_vector_type(4)));

// Load input element i as float, from either a bf16 or fp32 buffer.
__device__ __forceinline__ float ldin(const void* p, size_t i, int isbf) {
    if (isbf) {
        unsigned int u = ((const unsigned short*)p)[i];
        union { unsigned int ui; float f; } cv;
        cv.ui = u << 16;
        return cv.f;
    }
    return ((const float*)p)[i];
}

// Detect input dtype: sample even-index ushorts of x, decode as bf16.
// Genuine bf16 data -> |v| ~ N(0,1) (max ~6). fp32 data -> low-mantissa
// halves decode to log-uniform junk (huge exponents w.h.p.). flag=1 => bf16.
__global__ void detect_dtype(const void* x, int* flag) {
    __shared__ int bad;
    if (threadIdx.x == 0) bad = 0;
    __syncthreads();
    const unsigned short* u = (const unsigned short*)x;
    int mybad = 0;
    for (int k = 0; k < 16; ++k) {
        size_t i = (size_t)(threadIdx.x + k * 256) * 1987 + 3;  // < 8.2M (x has 16.7M elems)
        unsigned int b = u[2 * i];
        union { unsigned int ui; float f; } cv;
        cv.ui = b << 16;
        float v = cv.f;
        if (!(fabsf(v) < 1000.0f)) mybad = 1;  // catches huge / inf / nan
    }
    if (mybad) atomicOr(&bad, 1);
    __syncthreads();
    if (threadIdx.x == 0) *flag = (bad == 0) ? 1 : 0;
}

// ---------------- one-time setup ----------------

// WcatT hi/lo [c][k] fp16 of OPSCALE*W; c in [0,2048), k in [0,1536):
// k<512 -> Wx, <1024 -> Wh, else Wattn.
__global__ __launch_bounds__(256) void build_wcatT(const void* __restrict__ Wx,
                                                   const void* __restrict__ Wh,
                                                   const void* __restrict__ Wattn,
                                                   const int* __restrict__ flagp,
                                                   _Float16* __restrict__ WThi,
                                                   _Float16* __restrict__ WTlo) {
    int isbf = *flagp;
    __shared__ float tile[64][65];
    int k0 = blockIdx.x * 64;   // 24 blocks
    int c0 = blockIdx.y * 64;   // 32 blocks
    int tid = threadIdx.x;
    int cl = tid & 63;
    int kr = tid >> 6;
#pragma unroll
    for (int r = 0; r < 16; ++r) {
        int kl = kr * 16 + r;
        int k = k0 + kl;
        const void* src;
        size_t roff;
        if (k < 512)       { src = Wx;    roff = (size_t)k * 2048; }
        else if (k < 1024) { src = Wh;    roff = (size_t)(k - 512) * 2048; }
        else               { src = Wattn; roff = (size_t)(k - 1024) * 2048; }
        tile[kl][cl] = ldin(src, roff + c0 + cl, isbf);
    }
    __syncthreads();
    int kl2 = tid & 63;
    int cr = tid >> 6;
#pragma unroll
    for (int r = 0; r < 16; ++r) {
        int cl2 = cr * 16 + r;
        float v = tile[kl2][cl2] * OPSCALE;
        _Float16 hi = (_Float16)v;
        _Float16 lo = (_Float16)(v - (float)hi);
        size_t idx = (size_t)(c0 + cl2) * KTOT + k0 + kl2;
        WThi[idx] = hi;
        WTlo[idx] = lo;
    }
}

// h0 = c0 = mean over 16 spatial positions of A[n,h,:,:]
__global__ __launch_bounds__(256) void init_state(const void* __restrict__ A,
                                                  const int* __restrict__ flagp,
                                                  float* __restrict__ h,
                                                  float* __restrict__ c) {
    int isbf = *flagp;
    int n = blockIdx.x;
    int tid = threadIdx.x;
#pragma unroll
    for (int j = 0; j < 2; ++j) {
        int hh = tid * 2 + j;
        size_t base = ((size_t)n * 512 + hh) * 16;
        float s = 0.f;
#pragma unroll
        for (int p = 0; p < 16; ++p) s += ldin(A, base + p, isbf);
        s *= (1.0f / 16.0f);
        h[n * 512 + hh] = s;
        c[n * 512 + hh] = s;
    }
}

// ---------------- per-step kernels ----------------

__device__ __forceinline__ void split_store(_Float16* hi, _Float16* lo, int idx, float v) {
    float s = v * OPSCALE;
    _Float16 h = (_Float16)s;
    hi[idx] = h;
    lo[idx] = (_Float16)(s - (float)h);
}

// fp32 attention + build scaled hi/lo Acat: [0:512]=x_t, [512:1024]=h, [1024:1536]=attn
__global__ __launch_bounds__(256) void prep_step(const void* __restrict__ x,
                                                 const void* __restrict__ A,
                                                 const int* __restrict__ flagp,
                                                 const float* __restrict__ h,
                                                 _Float16* __restrict__ Ahi,
                                                 _Float16* __restrict__ Alo,
                                                 int t) {
    int isbf = *flagp;
    int n = blockIdx.x;
    int tid = threadIdx.x;
    int lane = tid & 63, wave = tid >> 6;
    __shared__ float wsum[4][16];

    int hh0 = tid * 2;
    size_t abase = ((size_t)n * 512 + hh0) * 16;
    float av[2][16];
    float hv[2];
#pragma unroll
    for (int j = 0; j < 2; ++j) {
        hv[j] = h[n * 512 + hh0 + j];
#pragma unroll
        for (int p = 0; p < 16; ++p) av[j][p] = ldin(A, abase + j * 16 + p, isbf);
    }
    float part[16];
#pragma unroll
    for (int p = 0; p < 16; ++p) part[p] = hv[0] * av[0][p] + hv[1] * av[1][p];
#pragma unroll
    for (int off = 32; off > 0; off >>= 1) {
#pragma unroll
        for (int p = 0; p < 16; ++p) part[p] += __shfl_down(part[p], off, 64);
    }
    if (lane == 0) {
#pragma unroll
        for (int p = 0; p < 16; ++p) wsum[wave][p] = part[p];
    }
    __syncthreads();

    const float scale = 0.04419417382415922f;  // 1/sqrt(512)
    float sc[16], m = -1e30f;
#pragma unroll
    for (int p = 0; p < 16; ++p) {
        sc[p] = (wsum[0][p] + wsum[1][p] + wsum[2][p] + wsum[3][p]) * scale;
        m = fmaxf(m, sc[p]);
    }
    float sum = 0.f;
#pragma unroll
    for (int p = 0; p < 16; ++p) { sc[p] = __expf(sc[p] - m); sum += sc[p]; }
    float inv = 1.0f / sum;

    _Float16* hrow = Ahi + (size_t)n * KTOT;
    _Float16* lrow = Alo + (size_t)n * KTOT;
    size_t xbase = ((size_t)n * TS + t) * 512;
#pragma unroll
    for (int j = 0; j < 2; ++j) {
        int hh = hh0 + j;
        float at = 0.f;
#pragma unroll
        for (int p = 0; p < 16; ++p) at += av[j][p] * sc[p];
        at *= inv;
        split_store(hrow, lrow, hh, ldin(x, xbase + hh, isbf));
        split_store(hrow, lrow, 512 + hh, hv[j]);
        split_store(hrow, lrow, 1024 + hh, at);
    }
}

// GEMM (32 batch rows x [4 gates x 64 hcols]) + fused LSTM epilogue.
// acc = Ahi*Bhi + Ahi*Blo + Alo*Bhi (fp32 accum), operands pre-scaled x64.
__global__ __launch_bounds__(256) void gemm_step(const _Float16* __restrict__ Ahi,
                                                 const _Float16* __restrict__ Alo,
                                                 const _Float16* __restrict__ WThi,
                                                 const _Float16* __restrict__ WTlo,
                                                 const void* __restrict__ bias,
                                                 const int* __restrict__ flagp,
                                                 float* __restrict__ h,
                                                 float* __restrict__ c,
                                                 void* __restrict__ out,
                                                 int t) {
    int isbf = *flagp;
    __shared__ __align__(16) unsigned short AldsH[32 * 72];
    __shared__ __align__(16) unsigned short AldsL[32 * 72];
    __shared__ __align__(16) unsigned short BldsH[256 * 72];
    __shared__ __align__(16) unsigned short BldsL[256 * 72];
    int tid = threadIdx.x;
    int lane = tid & 63, wave = tid >> 6;
    int bx = blockIdx.x;
    int ht = bx & 7, mt = bx >> 3;
    int M0 = mt * 32, HC0 = ht * 64;

    f32x4 acc[2][4];
#pragma unroll
    for (int i = 0; i < 2; ++i)
#pragma unroll
        for (int g = 0; g < 4; ++g) acc[i][g] = (f32x4){0.f, 0.f, 0.f, 0.f};

    int arow = tid >> 3;
    int kc = (tid & 7) * 8;

    for (int kk = 0; kk < KTOT / 64; ++kk) {
        int kbase = kk * 64;
        size_t aoff = (size_t)(M0 + arow) * KTOT + kbase + kc;
        *(uint4*)&AldsH[arow * 72 + kc] = *(const uint4*)(Ahi + aoff);
        *(uint4*)&AldsL[arow * 72 + kc] = *(const uint4*)(Alo + aoff);
#pragma unroll
        for (int r = 0; r < 8; ++r) {
            int lrow = r * 32 + (tid >> 3);
            int gcol = (lrow >> 6) * 512 + HC0 + (lrow & 63);
            size_t boff = (size_t)gcol * KTOT + kbase + kc;
            *(uint4*)&BldsH[lrow * 72 + kc] = *(const uint4*)(WThi + boff);
            *(uint4*)&BldsL[lrow * 72 + kc] = *(const uint4*)(WTlo + boff);
        }
        __syncthreads();
#pragma unroll
        for (int kf = 0; kf < 2; ++kf) {
            int ko = kf * 32 + (lane >> 4) * 8;
            f16x8 ah[2], al[2], bh[4], bl[4];
#pragma unroll
            for (int mi = 0; mi < 2; ++mi) {
                ah[mi] = *(const f16x8*)&AldsH[(mi * 16 + (lane & 15)) * 72 + ko];
                al[mi] = *(const f16x8*)&AldsL[(mi * 16 + (lane & 15)) * 72 + ko];
            }
#pragma unroll
            for (int g = 0; g < 4; ++g) {
                int brow = (g * 64 + wave * 16 + (lane & 15)) * 72 + ko;
                bh[g] = *(const f16x8*)&BldsH[brow];
                bl[g] = *(const f16x8*)&BldsL[brow];
            }
#pragma unroll
            for (int mi = 0; mi < 2; ++mi)
#pragma unroll
                for (int g = 0; g < 4; ++g) {
                    acc[mi][g] = __builtin_amdgcn_mfma_f32_16x16x32_f16(ah[mi], bh[g], acc[mi][g], 0, 0, 0);
                    acc[mi][g] = __builtin_amdgcn_mfma_f32_16x16x32_f16(ah[mi], bl[g], acc[mi][g], 0, 0, 0);
                    acc[mi][g] = __builtin_amdgcn_mfma_f32_16x16x32_f16(al[mi], bh[g], acc[mi][g], 0, 0, 0);
                }
        }
        __syncthreads();
    }

    int colh = HC0 + wave * 16 + (lane & 15);
    float bi = ldin(bias, colh, isbf);
    float bf = ldin(bias, 512 + colh, isbf);
    float bo = ldin(bias, 1024 + colh, isbf);
    float bg = ldin(bias, 1536 + colh, isbf);
#pragma unroll
    for (int mi = 0; mi < 2; ++mi) {
#pragma unroll
        for (int r = 0; r < 4; ++r) {
            int n = M0 + mi * 16 + (lane >> 4) * 4 + r;
            float xi = acc[mi][0][r] * INV_SCALE2 + bi;
            float xf = acc[mi][1][r] * INV_SCALE2 + bf;
            float xo = acc[mi][2][r] * INV_SCALE2 + bo;
            float xg = acc[mi][3][r] * INV_SCALE2 + bg;
            float iv = 1.f / (1.f + __expf(-xi));
            float fv = 1.f / (1.f + __expf(-xf));
            float ov = 1.f / (1.f + __expf(-xo));
            float gv = 1.f - 2.f / (__expf(2.f * xg) + 1.f);   // tanh
            float cold = c[n * 512 + colh];
            float cnew = fv * cold + iv * gv;
            float tc = 1.f - 2.f / (__expf(2.f * cnew) + 1.f); // tanh
            float hnew = ov * tc;
            c[n * 512 + colh] = cnew;
            h[n * 512 + colh] = hnew;
            size_t oidx = ((size_t)n * TS + t) * 512 + colh;
            if (isbf) ((__hip_bfloat16*)out)[oidx] = __float2bfloat16(hnew);
            else      ((float*)out)[oidx] = hnew;
        }
    }
}

// ---------------- launch ----------------

extern "C" void kernel_launch(void* const* d_in, const int* in_sizes, int n_in,
                              void* d_out, int out_size, void* d_ws, size_t ws_size,
                              hipStream_t stream) {
    const void* x     = d_in[0];
    const void* A     = d_in[1];
    const void* Wx    = d_in[2];
    const void* Wh    = d_in[3];
    const void* Wattn = d_in[4];
    const void* bias  = d_in[5];

    char* ws = (char*)d_ws;
    const size_t WSZ = (size_t)2048 * KTOT * 2;  // 6291456 B
    const size_t ASZ = (size_t)NB * KTOT * 2;    // 1572864 B
    _Float16* WThi = (_Float16*)ws;
    _Float16* WTlo = (_Float16*)(ws + WSZ);
    _Float16* Ahi  = (_Float16*)(ws + 2 * WSZ);
    _Float16* Alo  = (_Float16*)(ws + 2 * WSZ + ASZ);
    float* hbuf    = (float*)(ws + 2 * WSZ + 2 * ASZ);
    float* cbuf    = (float*)(ws + 2 * WSZ + 2 * ASZ + 1048576);
    int* flag      = (int*)(ws + 2 * WSZ + 2 * ASZ + 2 * 1048576);

    detect_dtype<<<1, 256, 0, stream>>>(x, flag);
    build_wcatT<<<dim3(24, 32), 256, 0, stream>>>(Wx, Wh, Wattn, flag, WThi, WTlo);
    init_state<<<512, 256, 0, stream>>>(A, flag, hbuf, cbuf);
    for (int t = 0; t < TS; ++t) {
        prep_step<<<512, 256, 0, stream>>>(x, A, flag, hbuf, Ahi, Alo, t);
        gemm_step<<<128, 256, 0, stream>>>(Ahi, Alo, WThi, WTlo, bias, flag,
                                           hbuf, cbuf, d_out, t);
    }
}